// Round 16
// baseline (243.303 us; speedup 1.0000x reference)
//
#include <hip/hip_runtime.h>
#include <hip/hip_bf16.h>
#include <math.h>

#define N_TOK 2048
#define H_DIM 768
#define E_NUM 64
#define I_DIM 256
#define TOPK 8
#define NPAIR (N_TOK * TOPK)

typedef __attribute__((ext_vector_type(8))) short short8;
typedef __attribute__((ext_vector_type(4))) short short4v;
typedef __attribute__((ext_vector_type(4))) float f32x4;

__device__ inline ushort f2bf(float f) {
  unsigned u = __builtin_bit_cast(unsigned, f);
  u += 0x7fffu + ((u >> 16) & 1u);
  return (ushort)(u >> 16);
}

__device__ inline float bf2f(ushort h) {
  return __builtin_bit_cast(float, (unsigned)h << 16);
}

__device__ inline unsigned pack2(float a, float b) {
  return (unsigned)f2bf(a) | ((unsigned)f2bf(b) << 16);
}

__device__ inline f32x4 mfma16(short8 a, short8 b, f32x4 c) {
  return __builtin_amdgcn_mfma_f32_16x16x32_bf16(a, b, c, 0, 0, 0);
}

__device__ __forceinline__ void gload_lds16(const ushort* g, ushort* l) {
  __builtin_amdgcn_global_load_lds(
      (const __attribute__((address_space(1))) unsigned int*)g,
      (__attribute__((address_space(3))) unsigned int*)l, 16, 0, 0);
}

// ---------------- x fp32 -> bf16 ----------------
__global__ __launch_bounds__(512) void cvt_x_kernel(const float* __restrict__ x,
                                                    ushort* __restrict__ xbf) {
  const int i = blockIdx.x * 512 + threadIdx.x;
  const float* s = x + (size_t)i * 8;
  short8 r;
  #pragma unroll
  for (int j = 0; j < 8; ++j) r[j] = (short)f2bf(s[j]);
  *(short8*)(xbf + (size_t)i * 8) = r;
}

// ---------------- Router GEMM (fp32, split-K): part[ks][t][e] --------------
#define RT_KC 256
__global__ __launch_bounds__(256) void router_gemm(const float* __restrict__ x,
                                                   const float* __restrict__ rw,
                                                   float* __restrict__ part) {
  const int t0 = blockIdx.x * 64, k0 = blockIdx.y * RT_KC;
  __shared__ float xs[64][68];
  __shared__ float ws[64][68];
  const int tid = threadIdx.x;
  const int tx = tid & 15, ty = tid >> 4;
  float acc[4][4] = {};
  for (int kc = 0; kc < RT_KC; kc += 64) {
    __syncthreads();
    {
      const int r = tid >> 2, q = tid & 3;
      const float4* srcx = (const float4*)&x[(size_t)(t0 + r) * H_DIM + k0 + kc];
      const float4* srcw = (const float4*)&rw[(size_t)r * H_DIM + k0 + kc];
      float4* dstx = (float4*)&xs[r][0];
      float4* dstw = (float4*)&ws[r][0];
      #pragma unroll
      for (int j = 0; j < 4; ++j) {
        dstx[q * 4 + j] = srcx[q * 4 + j];
        dstw[q * 4 + j] = srcw[q * 4 + j];
      }
    }
    __syncthreads();
    #pragma unroll
    for (int k4 = 0; k4 < 16; ++k4) {
      float4 a0 = *(float4*)&xs[ty * 4 + 0][k4 * 4];
      float4 a1 = *(float4*)&xs[ty * 4 + 1][k4 * 4];
      float4 a2 = *(float4*)&xs[ty * 4 + 2][k4 * 4];
      float4 a3 = *(float4*)&xs[ty * 4 + 3][k4 * 4];
      float4 b0 = *(float4*)&ws[tx * 4 + 0][k4 * 4];
      float4 b1 = *(float4*)&ws[tx * 4 + 1][k4 * 4];
      float4 b2 = *(float4*)&ws[tx * 4 + 2][k4 * 4];
      float4 b3 = *(float4*)&ws[tx * 4 + 3][k4 * 4];
      #define RFMA(i, j, av, bv) \
        acc[i][j] = fmaf(av.x, bv.x, fmaf(av.y, bv.y, fmaf(av.z, bv.z, fmaf(av.w, bv.w, acc[i][j]))))
      RFMA(0, 0, a0, b0); RFMA(0, 1, a0, b1); RFMA(0, 2, a0, b2); RFMA(0, 3, a0, b3);
      RFMA(1, 0, a1, b0); RFMA(1, 1, a1, b1); RFMA(1, 2, a1, b2); RFMA(1, 3, a1, b3);
      RFMA(2, 0, a2, b0); RFMA(2, 1, a2, b1); RFMA(2, 2, a2, b2); RFMA(2, 3, a2, b3);
      RFMA(3, 0, a3, b0); RFMA(3, 1, a3, b1); RFMA(3, 2, a3, b2); RFMA(3, 3, a3, b3);
      #undef RFMA
    }
  }
  float* pp = part + ((size_t)blockIdx.y * N_TOK + t0) * E_NUM;
  #pragma unroll
  for (int i = 0; i < 4; ++i)
    #pragma unroll
    for (int j = 0; j < 4; ++j)
      pp[(ty * 4 + i) * E_NUM + tx * 4 + j] = acc[i][j];
}

// ---------------- Router top-k: sum partials -> top8 -> renorm -------------
__global__ __launch_bounds__(256) void router_topk(const float* __restrict__ part,
                                                   int* __restrict__ topi,
                                                   float* __restrict__ topw) {
  const int t = blockIdx.x * 4 + (threadIdx.x >> 6);
  const int l = threadIdx.x & 63;
  float myv = part[(size_t)t * E_NUM + l] +
              part[((size_t)N_TOK + t) * E_NUM + l] +
              part[((size_t)2 * N_TOK + t) * E_NUM + l];
  float topv[TOPK]; int topx[TOPK];
  #pragma unroll
  for (int k = 0; k < TOPK; ++k) {
    float bv = myv; int bi = l;
    #pragma unroll
    for (int off = 32; off > 0; off >>= 1) {
      float ov = __shfl_xor(bv, off, 64);
      int oi = __shfl_xor(bi, off, 64);
      if (ov > bv || (ov == bv && oi < bi)) { bv = ov; bi = oi; }
    }
    topv[k] = bv; topx[k] = bi;
    if (l == bi) myv = -INFINITY;
  }
  if (l == 0) {
    float mx = topv[0], w[TOPK], s = 0.f;
    #pragma unroll
    for (int k = 0; k < TOPK; ++k) { w[k] = __expf(topv[k] - mx); s += w[k]; }
    float inv = 1.f / s;
    #pragma unroll
    for (int k = 0; k < TOPK; ++k) {
      topi[t * TOPK + k] = topx[k];
      topw[t * TOPK + k] = w[k] * inv;
    }
  }
}

// ---------------- Histogram (LDS atomics) + prefix, single block -----------
__global__ __launch_bounds__(256) void hist_prefix_kernel(const int* __restrict__ topi,
                                                          int* __restrict__ offsets) {
  __shared__ int h[E_NUM];
  const int tid = threadIdx.x;
  if (tid < E_NUM) h[tid] = 0;
  __syncthreads();
  for (int i = tid; i < NPAIR; i += 256) atomicAdd(&h[topi[i]], 1);
  __syncthreads();
  if (tid == 0) {
    int s = 0;
    for (int e = 0; e < E_NUM; ++e) { offsets[e] = s; s += h[e]; }
    offsets[E_NUM] = s;
  }
}

// ---------------- Scatter: two-pass per-wave ballot, ONE barrier -----------
__global__ __launch_bounds__(256) void scatter64(const int* __restrict__ topi,
                                                 const int* __restrict__ offsets,
                                                 int* __restrict__ toklist,
                                                 int* __restrict__ pairpos) {
  const int e = blockIdx.x;
  const int tid = threadIdx.x, l = tid & 63, w = tid >> 6;
  __shared__ int wcnt[4];
  int cnt = 0;
  for (int c = 0; c < NPAIR / 4; c += 64) {
    const int idx = w * (NPAIR / 4) + c + l;
    cnt += __popcll(__ballot(topi[idx] == e));
  }
  if (l == 0) wcnt[w] = cnt;
  __syncthreads();
  int base = offsets[e];
  for (int ww = 0; ww < 4; ++ww)
    if (ww < w) base += wcnt[ww];
  for (int c = 0; c < NPAIR / 4; c += 64) {
    const int idx = w * (NPAIR / 4) + c + l;
    const bool p = (topi[idx] == e);
    const unsigned long long m = __ballot(p);
    if (p) {
      const int pos = base + __popcll(m & ((1ull << l) - 1ull));
      toklist[pos] = idx >> 3;
      pairpos[idx] = pos;
    }
    base += __popcll(m);
  }
}

// ---------------- K1: fused fp32-weight gate/up MFMA + SwiGLU -> hmid ------
// XCD-grouped 1D grid: flat = u*32 + ib*8 + w; ez = u*8 + w. The 4 ib-blocks
// of one (e,z) land 8 apart -> same XCD -> one L2 merges their 4x256B
// quarter-row weight reads into sequential full-row HBM streams.
#define K1_TB 192
#define KC1 64
#define NCH1 12
#define BS_ST 74
#define K1_NZ 11
__global__ __launch_bounds__(512, 4) void k1_gateup(const ushort* __restrict__ xbf,
                                                    const float* __restrict__ wg,
                                                    const float* __restrict__ wu,
                                                    const int* __restrict__ offsets,
                                                    const int* __restrict__ toklist,
                                                    ushort* __restrict__ hmid) {
  const int flat = blockIdx.x;                 // [0, 2816) = 32*88
  const int ib = (flat >> 3) & 3;
  const int ez = (flat >> 5) * 8 + (flat & 7); // [0, 704)
  const int e = ez / K1_NZ, z = ez % K1_NZ;
  const int i0 = ib * 64;
  const int start = offsets[e], cnt = offsets[e + 1] - start;
  const int tokbase = z * K1_TB;
  if (tokbase >= cnt) return;
  const int cntb = min(K1_TB, cnt - tokbase);

  __shared__ __align__(16) ushort xs[2][K1_TB][64];
  __shared__ __align__(16) ushort Bs[128][BS_ST];
  __shared__ int tks[K1_TB];

  const int tid = threadIdx.x;
  if (tid < K1_TB) tks[tid] = toklist[start + tokbase + min(tid, cntb - 1)];
  __syncthreads();

  const int l = tid & 63, wid = tid >> 6;
  const int tf = wid & 3, icw = wid >> 2;
  const int la15 = l & 15;
  const int lxor = (l & 7) ^ ((l >> 3) & 7);

  const ushort* srcx0 = xbf + (size_t)tks[24 * wid + 0 + (l >> 3)] * H_DIM + lxor * 8;
  const ushort* srcx1 = xbf + (size_t)tks[24 * wid + 8 + (l >> 3)] * H_DIM + lxor * 8;
  const ushort* srcx2 = xbf + (size_t)tks[24 * wid + 16 + (l >> 3)] * H_DIM + lxor * 8;

  const int q = tid & 15, kp = tid >> 4;
  const float* wgp = wg + (size_t)e * H_DIM * I_DIM + i0 + 4 * q;
  const float* wup = wu + (size_t)e * H_DIM * I_DIM + i0 + 4 * q;

  f32x4 accg[3][2] = {};
  f32x4 accu[3][2] = {};
  const int ko = (l >> 4) * 8;

  float4 g0 = *(const float4*)(wgp + (size_t)(2 * kp) * I_DIM);
  float4 g1 = *(const float4*)(wgp + (size_t)(2 * kp + 1) * I_DIM);
  float4 u0 = *(const float4*)(wup + (size_t)(2 * kp) * I_DIM);
  float4 u1 = *(const float4*)(wup + (size_t)(2 * kp + 1) * I_DIM);
  gload_lds16(srcx0, &xs[0][24 * wid + 0][0]);
  gload_lds16(srcx1, &xs[0][24 * wid + 8][0]);
  gload_lds16(srcx2, &xs[0][24 * wid + 16][0]);

  for (int n = 0; n < NCH1; ++n) {
    const int cur = n & 1, nxt = cur ^ 1;
    *(unsigned*)&Bs[q * 4 + 0][2 * kp] = pack2(g0.x, g1.x);
    *(unsigned*)&Bs[q * 4 + 1][2 * kp] = pack2(g0.y, g1.y);
    *(unsigned*)&Bs[q * 4 + 2][2 * kp] = pack2(g0.z, g1.z);
    *(unsigned*)&Bs[q * 4 + 3][2 * kp] = pack2(g0.w, g1.w);
    *(unsigned*)&Bs[64 + q * 4 + 0][2 * kp] = pack2(u0.x, u1.x);
    *(unsigned*)&Bs[64 + q * 4 + 1][2 * kp] = pack2(u0.y, u1.y);
    *(unsigned*)&Bs[64 + q * 4 + 2][2 * kp] = pack2(u0.z, u1.z);
    *(unsigned*)&Bs[64 + q * 4 + 3][2 * kp] = pack2(u0.w, u1.w);
    if (n + 1 < NCH1) {
      const int kh = (n + 1) * KC1;
      g0 = *(const float4*)(wgp + (size_t)(kh + 2 * kp) * I_DIM);
      g1 = *(const float4*)(wgp + (size_t)(kh + 2 * kp + 1) * I_DIM);
      u0 = *(const float4*)(wup + (size_t)(kh + 2 * kp) * I_DIM);
      u1 = *(const float4*)(wup + (size_t)(kh + 2 * kp + 1) * I_DIM);
      gload_lds16(srcx0 + kh, &xs[nxt][24 * wid + 0][0]);
      gload_lds16(srcx1 + kh, &xs[nxt][24 * wid + 8][0]);
      gload_lds16(srcx2 + kh, &xs[nxt][24 * wid + 16][0]);
      asm volatile("s_waitcnt vmcnt(7) lgkmcnt(0)" ::: "memory");
      __builtin_amdgcn_sched_barrier(0);
      __builtin_amdgcn_s_barrier();
    } else {
      asm volatile("s_waitcnt vmcnt(0) lgkmcnt(0)" ::: "memory");
      __builtin_amdgcn_sched_barrier(0);
      __builtin_amdgcn_s_barrier();
    }
    #pragma unroll
    for (int ks = 0; ks < 2; ++ks) {
      const int kof = ks * 32 + ko;
      const int sg8 = ((ks * 4 + (l >> 4)) ^ (l & 7)) * 8;
      short8 bg0 = *(const short8*)&Bs[icw * 32 + la15][kof];
      short8 bg1 = *(const short8*)&Bs[icw * 32 + 16 + la15][kof];
      short8 bu0 = *(const short8*)&Bs[64 + icw * 32 + la15][kof];
      short8 bu1 = *(const short8*)&Bs[64 + icw * 32 + 16 + la15][kof];
      __builtin_amdgcn_s_setprio(1);
      #pragma unroll
      for (int rf = 0; rf < 3; ++rf) {
        short8 a = *(const short8*)&xs[cur][tf * 48 + rf * 16 + la15][sg8];
        accg[rf][0] = mfma16(a, bg0, accg[rf][0]);
        accg[rf][1] = mfma16(a, bg1, accg[rf][1]);
        accu[rf][0] = mfma16(a, bu0, accu[rf][0]);
        accu[rf][1] = mfma16(a, bu1, accu[rf][1]);
      }
      __builtin_amdgcn_s_setprio(0);
    }
    asm volatile("s_waitcnt lgkmcnt(0)" ::: "memory");
    __builtin_amdgcn_sched_barrier(0);
    __builtin_amdgcn_s_barrier();
  }

  ushort* tbuf = &xs[0][0][0];
  #pragma unroll
  for (int rf = 0; rf < 3; ++rf)
    #pragma unroll
    for (int c = 0; c < 2; ++c)
      #pragma unroll
      for (int jj = 0; jj < 4; ++jj) {
        const int row = tf * 48 + rf * 16 + (l >> 4) * 4 + jj;
        const int col = icw * 32 + c * 16 + la15;
        float g = accg[rf][c][jj];
        float hm = g / (1.f + __expf(-g)) * accu[rf][c][jj];
        tbuf[row * 72 + col] = f2bf(hm);
      }
  __syncthreads();
  #pragma unroll
  for (int p = 0; p < 2; ++p) {
    const int row = (tid >> 2) + p * 128, cs = tid & 3;
    if (row < cntb) {
      short8 v0 = *(const short8*)&tbuf[row * 72 + cs * 16];
      short8 v1 = *(const short8*)&tbuf[row * 72 + cs * 16 + 8];
      ushort* dst = hmid + (size_t)(start + tokbase + row) * I_DIM + i0 + cs * 16;
      *(short8*)dst = v0;
      *(short8*)(dst + 8) = v1;
    }
  }
}

// ---------------- K2: fused fp32-weight down-proj -> out_pairs (bf16) ------
// Same XCD-grouping: flat = u*32 + hs*8 + w; ez = u*8 + w in [0,512).
#define K2_TB 256
#define KC2 128
#define DS_ST 138
__global__ __launch_bounds__(512) void k2_down(const ushort* __restrict__ hmid,
                                               const float* __restrict__ wd,
                                               const int* __restrict__ offsets,
                                               ushort* __restrict__ out_pairs) {
  const int flat = blockIdx.x;                 // [0, 2048) = 32*64
  const int hs = (flat >> 3) & 3;
  const int ez = (flat >> 5) * 8 + (flat & 7); // [0, 512)
  const int e = ez >> 3, z = ez & 7;
  const int h0 = hs * 192;
  const int start = offsets[e], cnt = offsets[e + 1] - start;
  const int tokbase = z * K2_TB;
  if (tokbase >= cnt) return;
  const int tm = min(K2_TB, cnt - tokbase);

  __shared__ ushort Ds[192][DS_ST];

  const int tid = threadIdx.x, l = tid & 63, wid = tid >> 6;
  const int tf = wid & 3, ch = wid >> 2;
  const int la15 = l & 15;
  const int ko = (l >> 4) * 8;
  f32x4 acc[4][6] = {};

  int p[4];
  #pragma unroll
  for (int rf = 0; rf < 4; ++rf)
    p[rf] = min(start + tokbase + tf * 64 + rf * 16 + la15, NPAIR - 1);

  const float* wde = wd + (size_t)e * I_DIM * H_DIM;

  for (int kh = 0; kh < I_DIM; kh += KC2) {
    __syncthreads();
    #pragma unroll
    for (int it = 0; it < 6; ++it) {
      int idx = tid + it * 512;
      int qq = idx % 48, m = idx / 48;
      const int k0 = 2 * m;
      const float* src = wde + (size_t)(kh + k0) * H_DIM + h0 + qq * 4;
      float4 v0 = *(const float4*)src;
      float4 v1 = *(const float4*)(src + H_DIM);
      *(unsigned*)&Ds[qq * 4 + 0][k0] = pack2(v0.x, v1.x);
      *(unsigned*)&Ds[qq * 4 + 1][k0] = pack2(v0.y, v1.y);
      *(unsigned*)&Ds[qq * 4 + 2][k0] = pack2(v0.z, v1.z);
      *(unsigned*)&Ds[qq * 4 + 3][k0] = pack2(v0.w, v1.w);
    }
    __syncthreads();
    #pragma unroll
    for (int ks = 0; ks < 4; ++ks) {
      const int kof = ks * 32 + ko;
      short8 a[4];
      #pragma unroll
      for (int rf = 0; rf < 4; ++rf)
        a[rf] = *(const short8*)(hmid + (size_t)p[rf] * I_DIM + kh + kof);
      __builtin_amdgcn_s_setprio(1);
      #pragma unroll
      for (int cf = 0; cf < 6; ++cf) {
        short8 b = *(const short8*)&Ds[ch * 96 + cf * 16 + la15][kof];
        #pragma unroll
        for (int rf = 0; rf < 4; ++rf)
          acc[rf][cf] = mfma16(a[rf], b, acc[rf][cf]);
      }
      __builtin_amdgcn_s_setprio(0);
    }
  }

  const int rgrp = l >> 4;
  #pragma unroll
  for (int rf = 0; rf < 4; ++rf)
    #pragma unroll
    for (int jj = 0; jj < 4; ++jj) {
      int r = tf * 64 + rf * 16 + rgrp * 4 + jj;
      if (r < tm) {
        const size_t prow = (size_t)(start + tokbase + r);
        #pragma unroll
        for (int cf = 0; cf < 6; ++cf) {
          int hcol = h0 + ch * 96 + cf * 16 + la15;
          out_pairs[prow * H_DIM + hcol] = f2bf(acc[rf][cf][jj]);
        }
      }
    }
}

// ---------------- Gather-reduce: out[t] = sum_k w_k * out_pairs_bf[pos] ----
__global__ __launch_bounds__(192) void moe_reduce(const ushort* __restrict__ out_pairs,
                                                  const int* __restrict__ pairpos,
                                                  const float* __restrict__ topw,
                                                  float* __restrict__ out) {
  const int t = blockIdx.x;
  const int c = threadIdx.x;
  float4 acc = make_float4(0.f, 0.f, 0.f, 0.f);
  #pragma unroll
  for (int k = 0; k < TOPK; ++k) {
    const int pos = pairpos[t * TOPK + k];
    const float w = topw[t * TOPK + k];
    short4v v = *(const short4v*)&out_pairs[(size_t)pos * H_DIM + c * 4];
    acc.x = fmaf(w, bf2f((ushort)v[0]), acc.x);
    acc.y = fmaf(w, bf2f((ushort)v[1]), acc.y);
    acc.z = fmaf(w, bf2f((ushort)v[2]), acc.z);
    acc.w = fmaf(w, bf2f((ushort)v[3]), acc.w);
  }
  *(float4*)&out[(size_t)t * H_DIM + c * 4] = acc;
}

extern "C" void kernel_launch(void* const* d_in, const int* in_sizes, int n_in,
                              void* d_out, int out_size, void* d_ws, size_t ws_size,
                              hipStream_t stream) {
  const float* x  = (const float*)d_in[0];
  const float* rw = (const float*)d_in[1];
  const float* wg = (const float*)d_in[2];
  const float* wu = (const float*)d_in[3];
  const float* wd = (const float*)d_in[4];
  float* out = (float*)d_out;

  char* ws = (char*)d_ws;
  int*    topi     = (int*)(ws + 0);
  float*  topw     = (float*)(ws + 65536);
  int*    offsets  = (int*)(ws + 131072);
  int*    toklist  = (int*)(ws + 132608);
  int*    pairpos  = (int*)(ws + 264192);
  ushort* xbf      = (ushort*)(ws + 331776);   // 3 MB
  ushort* hmid     = (ushort*)(ws + 3477504);  // 8 MB
  float*  rpart    = (float*)(ws + 3477504);   // overlaps hmid; dead before k1
  ushort* out_pairs= (ushort*)(ws + 11866112); // 25.2 MB bf16

  cvt_x_kernel<<<(N_TOK * H_DIM / 8) / 512, 512, 0, stream>>>(x, xbf);
  router_gemm<<<dim3(N_TOK / 64, 3), 256, 0, stream>>>(x, rw, rpart);
  router_topk<<<N_TOK / 4, 256, 0, stream>>>(rpart, topi, topw);
  hist_prefix_kernel<<<1, 256, 0, stream>>>(topi, offsets);
  scatter64<<<E_NUM, 256, 0, stream>>>(topi, offsets, toklist, pairpos);
  // XCD-grouped 1D grids: 4*64*11 = 2816 = 32*88; 4*64*8 = 2048 = 32*64
  k1_gateup<<<2816, 512, 0, stream>>>(xbf, wg, wu, offsets, toklist, hmid);
  k2_down<<<2048, 512, 0, stream>>>(hmid, wd, offsets, out_pairs);
  moe_reduce<<<N_TOK, 192, 0, stream>>>(out_pairs, pairpos, topw, out);
}

// Round 17
// 127.223 us; speedup vs baseline: 1.9124x; 1.9124x over previous
//
#include <hip/hip_runtime.h>
#include <hip/hip_bf16.h>
#include <math.h>

#define N_TOK 2048
#define H_DIM 768
#define E_NUM 64
#define I_DIM 256
#define TOPK 8
#define NPAIR (N_TOK * TOPK)

typedef __attribute__((ext_vector_type(8))) short short8;
typedef __attribute__((ext_vector_type(4))) short short4v;
typedef __attribute__((ext_vector_type(4))) float f32x4;

__device__ inline ushort f2bf(float f) {
  unsigned u = __builtin_bit_cast(unsigned, f);
  u += 0x7fffu + ((u >> 16) & 1u);
  return (ushort)(u >> 16);
}

__device__ inline float bf2f(ushort h) {
  return __builtin_bit_cast(float, (unsigned)h << 16);
}

__device__ inline unsigned pack2(float a, float b) {
  return (unsigned)f2bf(a) | ((unsigned)f2bf(b) << 16);
}

__device__ inline f32x4 mfma16(short8 a, short8 b, f32x4 c) {
  return __builtin_amdgcn_mfma_f32_16x16x32_bf16(a, b, c, 0, 0, 0);
}

__device__ __forceinline__ void gload_lds16(const ushort* g, ushort* l) {
  __builtin_amdgcn_global_load_lds(
      (const __attribute__((address_space(1))) unsigned int*)g,
      (__attribute__((address_space(3))) unsigned int*)l, 16, 0, 0);
}

// ---------------- Router GEMM (fp32, split-K) + fused x->bf16 --------------
// Each (tile, ksplit) block owns a distinct x slab -> emits xbf once.
#define RT_KC 256
__global__ __launch_bounds__(256) void router_gemm(const float* __restrict__ x,
                                                   const float* __restrict__ rw,
                                                   float* __restrict__ part,
                                                   ushort* __restrict__ xbf) {
  const int t0 = blockIdx.x * 64, k0 = blockIdx.y * RT_KC;
  __shared__ float xs[64][68];
  __shared__ float ws[64][68];
  const int tid = threadIdx.x;
  const int tx = tid & 15, ty = tid >> 4;
  float acc[4][4] = {};
  for (int kc = 0; kc < RT_KC; kc += 64) {
    __syncthreads();
    {
      const int r = tid >> 2, q = tid & 3;
      const float4* srcx = (const float4*)&x[(size_t)(t0 + r) * H_DIM + k0 + kc];
      const float4* srcw = (const float4*)&rw[(size_t)r * H_DIM + k0 + kc];
      float4* dstx = (float4*)&xs[r][0];
      float4* dstw = (float4*)&ws[r][0];
      ushort* xb = xbf + (size_t)(t0 + r) * H_DIM + k0 + kc + q * 16;
      #pragma unroll
      for (int j = 0; j < 4; ++j) {
        float4 vx = srcx[q * 4 + j];
        dstx[q * 4 + j] = vx;
        dstw[q * 4 + j] = srcw[q * 4 + j];
        uint2 b;
        b.x = pack2(vx.x, vx.y);
        b.y = pack2(vx.z, vx.w);
        *(uint2*)(xb + j * 4) = b;
      }
    }
    __syncthreads();
    #pragma unroll
    for (int k4 = 0; k4 < 16; ++k4) {
      float4 a0 = *(float4*)&xs[ty * 4 + 0][k4 * 4];
      float4 a1 = *(float4*)&xs[ty * 4 + 1][k4 * 4];
      float4 a2 = *(float4*)&xs[ty * 4 + 2][k4 * 4];
      float4 a3 = *(float4*)&xs[ty * 4 + 3][k4 * 4];
      float4 b0 = *(float4*)&ws[tx * 4 + 0][k4 * 4];
      float4 b1 = *(float4*)&ws[tx * 4 + 1][k4 * 4];
      float4 b2 = *(float4*)&ws[tx * 4 + 2][k4 * 4];
      float4 b3 = *(float4*)&ws[tx * 4 + 3][k4 * 4];
      #define RFMA(i, j, av, bv) \
        acc[i][j] = fmaf(av.x, bv.x, fmaf(av.y, bv.y, fmaf(av.z, bv.z, fmaf(av.w, bv.w, acc[i][j]))))
      RFMA(0, 0, a0, b0); RFMA(0, 1, a0, b1); RFMA(0, 2, a0, b2); RFMA(0, 3, a0, b3);
      RFMA(1, 0, a1, b0); RFMA(1, 1, a1, b1); RFMA(1, 2, a1, b2); RFMA(1, 3, a1, b3);
      RFMA(2, 0, a2, b0); RFMA(2, 1, a2, b1); RFMA(2, 2, a2, b2); RFMA(2, 3, a2, b3);
      RFMA(3, 0, a3, b0); RFMA(3, 1, a3, b1); RFMA(3, 2, a3, b2); RFMA(3, 3, a3, b3);
      #undef RFMA
    }
  }
  float* pp = part + ((size_t)blockIdx.y * N_TOK + t0) * E_NUM;
  #pragma unroll
  for (int i = 0; i < 4; ++i)
    #pragma unroll
    for (int j = 0; j < 4; ++j)
      pp[(ty * 4 + i) * E_NUM + tx * 4 + j] = acc[i][j];
}

// ---------------- Router top-k: sum partials -> top8 -> renorm -------------
__global__ __launch_bounds__(256) void router_topk(const float* __restrict__ part,
                                                   int* __restrict__ topi,
                                                   float* __restrict__ topw) {
  const int t = blockIdx.x * 4 + (threadIdx.x >> 6);
  const int l = threadIdx.x & 63;
  float myv = part[(size_t)t * E_NUM + l] +
              part[((size_t)N_TOK + t) * E_NUM + l] +
              part[((size_t)2 * N_TOK + t) * E_NUM + l];
  float topv[TOPK]; int topx[TOPK];
  #pragma unroll
  for (int k = 0; k < TOPK; ++k) {
    float bv = myv; int bi = l;
    #pragma unroll
    for (int off = 32; off > 0; off >>= 1) {
      float ov = __shfl_xor(bv, off, 64);
      int oi = __shfl_xor(bi, off, 64);
      if (ov > bv || (ov == bv && oi < bi)) { bv = ov; bi = oi; }
    }
    topv[k] = bv; topx[k] = bi;
    if (l == bi) myv = -INFINITY;
  }
  if (l == 0) {
    float mx = topv[0], w[TOPK], s = 0.f;
    #pragma unroll
    for (int k = 0; k < TOPK; ++k) { w[k] = __expf(topv[k] - mx); s += w[k]; }
    float inv = 1.f / s;
    #pragma unroll
    for (int k = 0; k < TOPK; ++k) {
      topi[t * TOPK + k] = topx[k];
      topw[t * TOPK + k] = w[k] * inv;
    }
  }
}

// ---------------- Scatter + fused histogram/prefix, one block per expert ---
// Pass 1 builds the FULL 64-bin histogram (LDS atomics) + per-wave own-expert
// counts; thread 0 prefixes to get this expert's base and writes offsets[e]
// (block 63 also writes offsets[64]). Pass 2 does ordered ballot compaction.
__global__ __launch_bounds__(256) void scatter64(const int* __restrict__ topi,
                                                 int* __restrict__ offsets,
                                                 int* __restrict__ toklist,
                                                 int* __restrict__ pairpos) {
  const int e = blockIdx.x;
  const int tid = threadIdx.x, l = tid & 63, w = tid >> 6;
  __shared__ int h[E_NUM];
  __shared__ int wcnt[4];
  __shared__ int sbase;
  if (tid < E_NUM) h[tid] = 0;
  __syncthreads();
  int cnt = 0;
  for (int c = 0; c < NPAIR / 4; c += 64) {
    const int idx = w * (NPAIR / 4) + c + l;
    const int ei = topi[idx];
    atomicAdd(&h[ei], 1);
    cnt += __popcll(__ballot(ei == e));
  }
  if (l == 0) wcnt[w] = cnt;
  __syncthreads();
  if (tid == 0) {
    int s = 0;
    for (int ee = 0; ee < e; ++ee) s += h[ee];
    sbase = s;
    offsets[e] = s;
    if (e == E_NUM - 1) offsets[E_NUM] = s + h[e];
  }
  __syncthreads();
  int base = sbase;
  for (int ww = 0; ww < 4; ++ww)
    if (ww < w) base += wcnt[ww];
  for (int c = 0; c < NPAIR / 4; c += 64) {
    const int idx = w * (NPAIR / 4) + c + l;
    const bool p = (topi[idx] == e);
    const unsigned long long m = __ballot(p);
    if (p) {
      const int pos = base + __popcll(m & ((1ull << l) - 1ull));
      toklist[pos] = idx >> 3;
      pairpos[idx] = pos;
    }
    base += __popcll(m);
  }
}

// ---------------- K1: fused fp32-weight gate/up MFMA + SwiGLU -> hmid ------
// (identical to the R15 passing kernel; dim3 grid)
#define K1_TB 192
#define KC1 64
#define NCH1 12
#define BS_ST 74
__global__ __launch_bounds__(512, 4) void k1_gateup(const ushort* __restrict__ xbf,
                                                    const float* __restrict__ wg,
                                                    const float* __restrict__ wu,
                                                    const int* __restrict__ offsets,
                                                    const int* __restrict__ toklist,
                                                    ushort* __restrict__ hmid) {
  const int e = blockIdx.y, ib = blockIdx.x;
  const int i0 = ib * 64;
  const int start = offsets[e], cnt = offsets[e + 1] - start;
  const int tokbase = blockIdx.z * K1_TB;
  if (tokbase >= cnt) return;
  const int cntb = min(K1_TB, cnt - tokbase);

  __shared__ __align__(16) ushort xs[2][K1_TB][64];
  __shared__ __align__(16) ushort Bs[128][BS_ST];
  __shared__ int tks[K1_TB];

  const int tid = threadIdx.x;
  if (tid < K1_TB) tks[tid] = toklist[start + tokbase + min(tid, cntb - 1)];
  __syncthreads();

  const int l = tid & 63, wid = tid >> 6;
  const int tf = wid & 3, icw = wid >> 2;
  const int la15 = l & 15;
  const int lxor = (l & 7) ^ ((l >> 3) & 7);

  const ushort* srcx0 = xbf + (size_t)tks[24 * wid + 0 + (l >> 3)] * H_DIM + lxor * 8;
  const ushort* srcx1 = xbf + (size_t)tks[24 * wid + 8 + (l >> 3)] * H_DIM + lxor * 8;
  const ushort* srcx2 = xbf + (size_t)tks[24 * wid + 16 + (l >> 3)] * H_DIM + lxor * 8;

  const int q = tid & 15, kp = tid >> 4;
  const float* wgp = wg + (size_t)e * H_DIM * I_DIM + i0 + 4 * q;
  const float* wup = wu + (size_t)e * H_DIM * I_DIM + i0 + 4 * q;

  f32x4 accg[3][2] = {};
  f32x4 accu[3][2] = {};
  const int ko = (l >> 4) * 8;

  float4 g0 = *(const float4*)(wgp + (size_t)(2 * kp) * I_DIM);
  float4 g1 = *(const float4*)(wgp + (size_t)(2 * kp + 1) * I_DIM);
  float4 u0 = *(const float4*)(wup + (size_t)(2 * kp) * I_DIM);
  float4 u1 = *(const float4*)(wup + (size_t)(2 * kp + 1) * I_DIM);
  gload_lds16(srcx0, &xs[0][24 * wid + 0][0]);
  gload_lds16(srcx1, &xs[0][24 * wid + 8][0]);
  gload_lds16(srcx2, &xs[0][24 * wid + 16][0]);

  for (int n = 0; n < NCH1; ++n) {
    const int cur = n & 1, nxt = cur ^ 1;
    *(unsigned*)&Bs[q * 4 + 0][2 * kp] = pack2(g0.x, g1.x);
    *(unsigned*)&Bs[q * 4 + 1][2 * kp] = pack2(g0.y, g1.y);
    *(unsigned*)&Bs[q * 4 + 2][2 * kp] = pack2(g0.z, g1.z);
    *(unsigned*)&Bs[q * 4 + 3][2 * kp] = pack2(g0.w, g1.w);
    *(unsigned*)&Bs[64 + q * 4 + 0][2 * kp] = pack2(u0.x, u1.x);
    *(unsigned*)&Bs[64 + q * 4 + 1][2 * kp] = pack2(u0.y, u1.y);
    *(unsigned*)&Bs[64 + q * 4 + 2][2 * kp] = pack2(u0.z, u1.z);
    *(unsigned*)&Bs[64 + q * 4 + 3][2 * kp] = pack2(u0.w, u1.w);
    if (n + 1 < NCH1) {
      const int kh = (n + 1) * KC1;
      g0 = *(const float4*)(wgp + (size_t)(kh + 2 * kp) * I_DIM);
      g1 = *(const float4*)(wgp + (size_t)(kh + 2 * kp + 1) * I_DIM);
      u0 = *(const float4*)(wup + (size_t)(kh + 2 * kp) * I_DIM);
      u1 = *(const float4*)(wup + (size_t)(kh + 2 * kp + 1) * I_DIM);
      gload_lds16(srcx0 + kh, &xs[nxt][24 * wid + 0][0]);
      gload_lds16(srcx1 + kh, &xs[nxt][24 * wid + 8][0]);
      gload_lds16(srcx2 + kh, &xs[nxt][24 * wid + 16][0]);
      asm volatile("s_waitcnt vmcnt(7) lgkmcnt(0)" ::: "memory");
      __builtin_amdgcn_sched_barrier(0);
      __builtin_amdgcn_s_barrier();
    } else {
      asm volatile("s_waitcnt vmcnt(0) lgkmcnt(0)" ::: "memory");
      __builtin_amdgcn_sched_barrier(0);
      __builtin_amdgcn_s_barrier();
    }
    #pragma unroll
    for (int ks = 0; ks < 2; ++ks) {
      const int kof = ks * 32 + ko;
      const int sg8 = ((ks * 4 + (l >> 4)) ^ (l & 7)) * 8;
      short8 bg0 = *(const short8*)&Bs[icw * 32 + la15][kof];
      short8 bg1 = *(const short8*)&Bs[icw * 32 + 16 + la15][kof];
      short8 bu0 = *(const short8*)&Bs[64 + icw * 32 + la15][kof];
      short8 bu1 = *(const short8*)&Bs[64 + icw * 32 + 16 + la15][kof];
      __builtin_amdgcn_s_setprio(1);
      #pragma unroll
      for (int rf = 0; rf < 3; ++rf) {
        short8 a = *(const short8*)&xs[cur][tf * 48 + rf * 16 + la15][sg8];
        accg[rf][0] = mfma16(a, bg0, accg[rf][0]);
        accg[rf][1] = mfma16(a, bg1, accg[rf][1]);
        accu[rf][0] = mfma16(a, bu0, accu[rf][0]);
        accu[rf][1] = mfma16(a, bu1, accu[rf][1]);
      }
      __builtin_amdgcn_s_setprio(0);
    }
    asm volatile("s_waitcnt lgkmcnt(0)" ::: "memory");
    __builtin_amdgcn_sched_barrier(0);
    __builtin_amdgcn_s_barrier();
  }

  ushort* tbuf = &xs[0][0][0];
  #pragma unroll
  for (int rf = 0; rf < 3; ++rf)
    #pragma unroll
    for (int c = 0; c < 2; ++c)
      #pragma unroll
      for (int jj = 0; jj < 4; ++jj) {
        const int row = tf * 48 + rf * 16 + (l >> 4) * 4 + jj;
        const int col = icw * 32 + c * 16 + la15;
        float g = accg[rf][c][jj];
        float hm = g / (1.f + __expf(-g)) * accu[rf][c][jj];
        tbuf[row * 72 + col] = f2bf(hm);
      }
  __syncthreads();
  #pragma unroll
  for (int p = 0; p < 2; ++p) {
    const int row = (tid >> 2) + p * 128, cs = tid & 3;
    if (row < cntb) {
      short8 v0 = *(const short8*)&tbuf[row * 72 + cs * 16];
      short8 v1 = *(const short8*)&tbuf[row * 72 + cs * 16 + 8];
      ushort* dst = hmid + (size_t)(start + tokbase + row) * I_DIM + i0 + cs * 16;
      *(short8*)dst = v0;
      *(short8*)(dst + 8) = v1;
    }
  }
}

// ---------------- K2: fused fp32-weight down-proj -> out_pairs (bf16) ------
// (identical to the R15 passing kernel; dim3 grid)
#define K2_TB 256
#define KC2 128
#define DS_ST 138
__global__ __launch_bounds__(512) void k2_down(const ushort* __restrict__ hmid,
                                               const float* __restrict__ wd,
                                               const int* __restrict__ offsets,
                                               ushort* __restrict__ out_pairs) {
  const int e = blockIdx.y, hs = blockIdx.x;
  const int h0 = hs * 192;
  const int start = offsets[e], cnt = offsets[e + 1] - start;
  const int tokbase = blockIdx.z * K2_TB;
  if (tokbase >= cnt) return;
  const int tm = min(K2_TB, cnt - tokbase);

  __shared__ ushort Ds[192][DS_ST];

  const int tid = threadIdx.x, l = tid & 63, wid = tid >> 6;
  const int tf = wid & 3, ch = wid >> 2;
  const int la15 = l & 15;
  const int ko = (l >> 4) * 8;
  f32x4 acc[4][6] = {};

  int p[4];
  #pragma unroll
  for (int rf = 0; rf < 4; ++rf)
    p[rf] = min(start + tokbase + tf * 64 + rf * 16 + la15, NPAIR - 1);

  const float* wde = wd + (size_t)e * I_DIM * H_DIM;

  for (int kh = 0; kh < I_DIM; kh += KC2) {
    __syncthreads();
    #pragma unroll
    for (int it = 0; it < 6; ++it) {
      int idx = tid + it * 512;
      int qq = idx % 48, m = idx / 48;
      const int k0 = 2 * m;
      const float* src = wde + (size_t)(kh + k0) * H_DIM + h0 + qq * 4;
      float4 v0 = *(const float4*)src;
      float4 v1 = *(const float4*)(src + H_DIM);
      *(unsigned*)&Ds[qq * 4 + 0][k0] = pack2(v0.x, v1.x);
      *(unsigned*)&Ds[qq * 4 + 1][k0] = pack2(v0.y, v1.y);
      *(unsigned*)&Ds[qq * 4 + 2][k0] = pack2(v0.z, v1.z);
      *(unsigned*)&Ds[qq * 4 + 3][k0] = pack2(v0.w, v1.w);
    }
    __syncthreads();
    #pragma unroll
    for (int ks = 0; ks < 4; ++ks) {
      const int kof = ks * 32 + ko;
      short8 a[4];
      #pragma unroll
      for (int rf = 0; rf < 4; ++rf)
        a[rf] = *(const short8*)(hmid + (size_t)p[rf] * I_DIM + kh + kof);
      __builtin_amdgcn_s_setprio(1);
      #pragma unroll
      for (int cf = 0; cf < 6; ++cf) {
        short8 b = *(const short8*)&Ds[ch * 96 + cf * 16 + la15][kof];
        #pragma unroll
        for (int rf = 0; rf < 4; ++rf)
          acc[rf][cf] = mfma16(a[rf], b, acc[rf][cf]);
      }
      __builtin_amdgcn_s_setprio(0);
    }
  }

  const int rgrp = l >> 4;
  #pragma unroll
  for (int rf = 0; rf < 4; ++rf)
    #pragma unroll
    for (int jj = 0; jj < 4; ++jj) {
      int r = tf * 64 + rf * 16 + rgrp * 4 + jj;
      if (r < tm) {
        const size_t prow = (size_t)(start + tokbase + r);
        #pragma unroll
        for (int cf = 0; cf < 6; ++cf) {
          int hcol = h0 + ch * 96 + cf * 16 + la15;
          out_pairs[prow * H_DIM + hcol] = f2bf(acc[rf][cf][jj]);
        }
      }
    }
}

// ---------------- Gather-reduce: out[t] = sum_k w_k * out_pairs_bf[pos] ----
__global__ __launch_bounds__(192) void moe_reduce(const ushort* __restrict__ out_pairs,
                                                  const int* __restrict__ pairpos,
                                                  const float* __restrict__ topw,
                                                  float* __restrict__ out) {
  const int t = blockIdx.x;
  const int c = threadIdx.x;
  float4 acc = make_float4(0.f, 0.f, 0.f, 0.f);
  #pragma unroll
  for (int k = 0; k < TOPK; ++k) {
    const int pos = pairpos[t * TOPK + k];
    const float w = topw[t * TOPK + k];
    short4v v = *(const short4v*)&out_pairs[(size_t)pos * H_DIM + c * 4];
    acc.x = fmaf(w, bf2f((ushort)v[0]), acc.x);
    acc.y = fmaf(w, bf2f((ushort)v[1]), acc.y);
    acc.z = fmaf(w, bf2f((ushort)v[2]), acc.z);
    acc.w = fmaf(w, bf2f((ushort)v[3]), acc.w);
  }
  *(float4*)&out[(size_t)t * H_DIM + c * 4] = acc;
}

extern "C" void kernel_launch(void* const* d_in, const int* in_sizes, int n_in,
                              void* d_out, int out_size, void* d_ws, size_t ws_size,
                              hipStream_t stream) {
  const float* x  = (const float*)d_in[0];
  const float* rw = (const float*)d_in[1];
  const float* wg = (const float*)d_in[2];
  const float* wu = (const float*)d_in[3];
  const float* wd = (const float*)d_in[4];
  float* out = (float*)d_out;

  char* ws = (char*)d_ws;
  int*    topi     = (int*)(ws + 0);
  float*  topw     = (float*)(ws + 65536);
  int*    offsets  = (int*)(ws + 131072);
  int*    toklist  = (int*)(ws + 132608);
  int*    pairpos  = (int*)(ws + 264192);
  ushort* xbf      = (ushort*)(ws + 331776);   // 3 MB
  ushort* hmid     = (ushort*)(ws + 3477504);  // 8 MB
  float*  rpart    = (float*)(ws + 3477504);   // overlaps hmid; dead before k1
  ushort* out_pairs= (ushort*)(ws + 11866112); // 25.2 MB bf16

  router_gemm<<<dim3(N_TOK / 64, 3), 256, 0, stream>>>(x, rw, rpart, xbf);
  router_topk<<<N_TOK / 4, 256, 0, stream>>>(rpart, topi, topw);
  scatter64<<<E_NUM, 256, 0, stream>>>(topi, offsets, toklist, pairpos);
  k1_gateup<<<dim3(4, E_NUM, 11), 512, 0, stream>>>(xbf, wg, wu, offsets, toklist, hmid);
  k2_down<<<dim3(4, E_NUM, 8), 512, 0, stream>>>(hmid, wd, offsets, out_pairs);
  moe_reduce<<<N_TOK, 192, 0, stream>>>(out_pairs, pairpos, topw, out);
}